// Round 2
// baseline (1529.859 us; speedup 1.0000x reference)
//
#include <hip/hip_runtime.h>

// Anti-alias filter: reflect-pad -> grouped conv (256->72, G=8, 3x3) -> BN ->
// softmax(72) -> per-pixel 9-tap weighted sum per channel.
// Shapes fixed: N=16, C=256, H=W=128, G=8, K=3, NCH=G*K*K=72, CPG=32.
// All tensors fp32 (per reference dtypes).

#define NN    16
#define CTOT  256
#define HH    128
#define WW    128
#define NG    8
#define CPG   32      // channels per group
#define NCH   72      // G*K*K conv output channels
#define BN_EPS 1e-5f

// ---- prep: BN scale/bias into ws ----
// ws layout (floats): [0,72) = scale, [72,144) = bias.
__global__ void aaf_prep(const float* __restrict__ gamma,
                         const float* __restrict__ beta,
                         const float* __restrict__ rmean,
                         const float* __restrict__ rvar,
                         float* __restrict__ ws) {
    int t = threadIdx.x;
    if (t < NCH) {
        float sc = gamma[t] * rsqrtf(rvar[t] + BN_EPS);
        ws[t]       = sc;
        ws[NCH + t] = beta[t] - rmean[t] * sc;
    }
}

// ---- main: one thread per output pixel (n,h,w) ----
__global__ __launch_bounds__(256) void aaf_main(
    const float* __restrict__ x,
    const float* __restrict__ wf,     // fp32 conv weights OIHW flat (uniform -> s_load)
    const float* __restrict__ scale,  // fp32 BN scale (72)
    const float* __restrict__ bias,   // fp32 BN bias  (72)
    float* __restrict__ out) {

    int idx = blockIdx.x * blockDim.x + threadIdx.x;  // n*H*W + h*W + w
    int n  = idx >> 14;           // H*W = 16384 = 2^14
    int hw = idx & 16383;
    int h  = hw >> 7;
    int w  = hw & 127;

    // reflection-pad neighbor indices (pad=1): -1 -> 1, 128 -> 126
    int ys[3], xs[3];
    ys[0] = (h == 0)   ? 1   : h - 1;
    ys[1] = h;
    ys[2] = (h == 127) ? 126 : h + 1;
    xs[0] = (w == 0)   ? 1   : w - 1;
    xs[1] = w;
    xs[2] = (w == 127) ? 126 : w + 1;

    const float* xb = x + ((size_t)n << 22);   // n * C*H*W, C*H*W = 2^22

    float sig[NCH];
#pragma unroll
    for (int i = 0; i < NCH; i++) sig[i] = 0.f;

    // ---- grouped conv: sig[g*9+o] = sum_{ci,tap} x * w ----
    // g unrolled so sig[] indices are compile-time constants (registers).
#pragma unroll
    for (int g = 0; g < NG; g++) {
        for (int ci = 0; ci < CPG; ci++) {
            const float* xc = xb + (((size_t)(g * CPG + ci)) << 14);
            float v[9];
#pragma unroll
            for (int ky = 0; ky < 3; ky++) {
                int rb = ys[ky] << 7;
#pragma unroll
                for (int kx = 0; kx < 3; kx++)
                    v[ky * 3 + kx] = xc[rb + xs[kx]];
            }
            // weights: wf[(g*9+o)*288 + ci*9 + tap] — wave-uniform indices
            const float* wb = wf + (size_t)(g * 9) * (CPG * 9) + ci * 9;
#pragma unroll
            for (int o = 0; o < 9; o++) {
                float a = sig[g * 9 + o];
#pragma unroll
                for (int tp = 0; tp < 9; tp++)
                    a = fmaf(v[tp], wb[o * (CPG * 9) + tp], a);
                sig[g * 9 + o] = a;
            }
        }
    }

    // ---- BN + softmax over all 72 channels ----
    float mx = -3.0e38f;
#pragma unroll
    for (int i = 0; i < NCH; i++) {
        sig[i] = fmaf(sig[i], scale[i], bias[i]);
        mx = fmaxf(mx, sig[i]);
    }
    float s = 0.f;
#pragma unroll
    for (int i = 0; i < NCH; i++) {
        sig[i] = __expf(sig[i] - mx);
        s += sig[i];
    }
    float inv = 1.f / s;
#pragma unroll
    for (int i = 0; i < NCH; i++) sig[i] *= inv;

    // ---- weighted 9-tap sum per channel ----
    size_t obase = ((size_t)n << 22) + (size_t)hw;
#pragma unroll
    for (int g = 0; g < NG; g++) {
        for (int ci = 0; ci < CPG; ci++) {
            int c = g * CPG + ci;
            const float* xc = xb + ((size_t)c << 14);
            float a = 0.f;
#pragma unroll
            for (int ky = 0; ky < 3; ky++) {
                int rb = ys[ky] << 7;
#pragma unroll
                for (int kx = 0; kx < 3; kx++)
                    a = fmaf(xc[rb + xs[kx]], sig[g * 9 + ky * 3 + kx], a);
            }
            out[obase + ((size_t)c << 14)] = a;
        }
    }
}

extern "C" void kernel_launch(void* const* d_in, const int* in_sizes, int n_in,
                              void* d_out, int out_size, void* d_ws, size_t ws_size,
                              hipStream_t stream) {
    const float* x     = (const float*)d_in[0];
    const float* cw    = (const float*)d_in[1];
    const float* gamma = (const float*)d_in[2];
    const float* beta  = (const float*)d_in[3];
    const float* rmean = (const float*)d_in[4];
    const float* rvar  = (const float*)d_in[5];
    float* out = (float*)d_out;
    float* ws  = (float*)d_ws;   // needs 144*4 = 576 B

    hipLaunchKernelGGL(aaf_prep, dim3(1), dim3(128), 0, stream,
                       gamma, beta, rmean, rvar, ws);

    int pixels = NN * HH * WW;          // 262144
    hipLaunchKernelGGL(aaf_main, dim3(pixels / 256), dim3(256), 0, stream,
                       x, cw, ws, ws + NCH, out);
}